// Round 1
// baseline (670.836 us; speedup 1.0000x reference)
//
#include <hip/hip_runtime.h>
#include <hip/hip_bf16.h>
#include <hip/hip_fp16.h>

#define N_TOK 524288
#define DM 256
#define HID 512
#define OUTD 32
#define NTYPE 4
#define BM 128
#define HC 64

typedef _Float16 half8 __attribute__((ext_vector_type(8)));
typedef float f32x4 __attribute__((ext_vector_type(4)));

// ---------------- prep kernels ----------------

__global__ void hist_kernel(const int* __restrict__ types, int* __restrict__ counts) {
    __shared__ int lc[NTYPE];
    int tid = threadIdx.x;
    if (tid < NTYPE) lc[tid] = 0;
    __syncthreads();
    int c0 = 0, c1 = 0, c2 = 0, c3 = 0;
    int stride = gridDim.x * blockDim.x;
    for (int i = blockIdx.x * blockDim.x + tid; i < N_TOK; i += stride) {
        int t = types[i];
        c0 += (t == 0); c1 += (t == 1); c2 += (t == 2); c3 += (t == 3);
    }
    atomicAdd(&lc[0], c0); atomicAdd(&lc[1], c1);
    atomicAdd(&lc[2], c2); atomicAdd(&lc[3], c3);
    __syncthreads();
    if (tid < NTYPE) atomicAdd(&counts[tid], lc[tid]);
}

__global__ void scan_kernel(int* __restrict__ meta) {
    // meta[0..3]=counts, meta[4..7]=offsets, meta[8..11]=cursors
    if (threadIdx.x == 0) {
        int off = 0;
        for (int t = 0; t < NTYPE; ++t) {
            meta[4 + t] = off;
            meta[8 + t] = off;
            off += meta[t];
        }
    }
}

__global__ void scatter_kernel(const int* __restrict__ types,
                               int* __restrict__ cursors,
                               int* __restrict__ idx) {
    int lane = threadIdx.x & 63;
    int stride = gridDim.x * blockDim.x;
    for (int i = blockIdx.x * blockDim.x + threadIdx.x; i < N_TOK; i += stride) {
        int t = types[i];
        #pragma unroll
        for (int tt = 0; tt < NTYPE; ++tt) {
            unsigned long long mask = __ballot(t == tt);
            if (t == tt) {
                int leader = __ffsll((unsigned long long)mask) - 1;
                int cnt = __popcll(mask);
                int base = 0;
                if (lane == leader) base = atomicAdd(&cursors[tt], cnt);
                base = __shfl(base, leader);
                int rank = __popcll(mask & ((1ull << lane) - 1ull));
                idx[base + rank] = i;
            }
        }
    }
}

__global__ void wprep_kernel(const float* __restrict__ W1, const float* __restrict__ W2,
                             _Float16* __restrict__ W1T, _Float16* __restrict__ W2T) {
    int i = blockIdx.x * blockDim.x + threadIdx.x;
    if (i < NTYPE * HID * DM) {
        int t = i / (HID * DM);
        int r = i - t * HID * DM;
        int h = r / DM;
        int d = r - h * DM;
        W1T[i] = (_Float16)W1[(t * DM + d) * HID + h];
    }
    if (i < NTYPE * OUTD * HID) {
        int t = i / (OUTD * HID);
        int r = i - t * OUTD * HID;
        int o = r / HID;
        int h = r - o * HID;
        W2T[i] = (_Float16)W2[(t * HID + h) * OUTD + o];
    }
}

// ---------------- fused grouped MLP ----------------
// Block: 256 threads (4 waves). Each block = 128 gathered rows of one type.
// X fragments live in registers. Per hidden-chunk (64): stage W1T/W2T chunk in
// swizzled LDS, GEMM1 -> relu -> Hs (LDS) -> GEMM2 accumulates persistent acc2.

__launch_bounds__(256)
__global__ void fused_mlp_kernel(const float* __restrict__ x,
                                 const int* __restrict__ meta,
                                 const int* __restrict__ idx,
                                 const _Float16* __restrict__ W1T,
                                 const _Float16* __restrict__ W2T,
                                 const float* __restrict__ b1,
                                 const float* __restrict__ b2,
                                 float* __restrict__ out) {
    const int t = blockIdx.y;
    const int cnt = meta[t];
    const int row_base = blockIdx.x * BM;
    if (row_base >= cnt) return;
    const int off = meta[4 + t];
    const int* idx_t = idx + off;

    __shared__ __align__(16) char W1sB[HC * 512];    // [64 h][256 d] f16, swizzled rows
    __shared__ __align__(16) char HsB[BM * 128];     // [128 m][64 h] f16, swizzled rows
    __shared__ __align__(16) char W2sB[OUTD * 128];  // [32 o][64 h] f16, swizzled rows

    const int tid = threadIdx.x;
    const int wave = tid >> 6;
    const int lane = tid & 63;
    const int l15 = lane & 15;
    const int lg = lane >> 4;  // 0..3

    // ---- load X fragments (gathered, fp32 -> f16) into registers ----
    half8 afrag[2][8];
    #pragma unroll
    for (int mt = 0; mt < 2; ++mt) {
        int rl = wave * 32 + mt * 16 + l15;
        int rglob = idx_t[min(row_base + rl, cnt - 1)];
        const float* xr = x + (size_t)rglob * DM;
        #pragma unroll
        for (int kk = 0; kk < 8; ++kk) {
            int k0 = kk * 32 + lg * 8;
            float4 v0 = *(const float4*)(xr + k0);
            float4 v1 = *(const float4*)(xr + k0 + 4);
            half8 h;
            h[0] = (_Float16)v0.x; h[1] = (_Float16)v0.y;
            h[2] = (_Float16)v0.z; h[3] = (_Float16)v0.w;
            h[4] = (_Float16)v1.x; h[5] = (_Float16)v1.y;
            h[6] = (_Float16)v1.z; h[7] = (_Float16)v1.w;
            afrag[mt][kk] = h;
        }
    }

    const f32x4 fzero = {0.f, 0.f, 0.f, 0.f};
    f32x4 acc2[2][2];
    #pragma unroll
    for (int mt = 0; mt < 2; ++mt)
        #pragma unroll
        for (int nt = 0; nt < 2; ++nt)
            acc2[mt][nt] = fzero;

    const _Float16* w1t_t = W1T + (size_t)t * HID * DM;   // [h][d]
    const _Float16* w2t_t = W2T + (size_t)t * OUTD * HID; // [o][h]

    for (int hc = 0; hc < HID / HC; ++hc) {
        __syncthreads();  // previous chunk's LDS readers done

        // stage W1 chunk: 64 rows x 256 f16 (2048 groups of 8)
        {
            const _Float16* src = w1t_t + hc * HC * DM;
            #pragma unroll
            for (int it = 0; it < 8; ++it) {
                int g = it * 256 + tid;
                int hr = g >> 5;
                int k0 = (g & 31) * 8;
                half8 v = *(const half8*)(src + hr * DM + k0);
                *(half8*)(W1sB + hr * 512 + ((k0 * 2) ^ ((hr & 7) << 4))) = v;
            }
        }
        // stage W2 chunk: 32 rows x 64 f16 (256 groups of 8)
        {
            int orow = tid >> 3;
            int k0 = (tid & 7) * 8;
            half8 v = *(const half8*)(w2t_t + orow * HID + hc * HC + k0);
            *(half8*)(W2sB + orow * 128 + ((k0 * 2) ^ ((orow & 7) << 4))) = v;
        }
        __syncthreads();

        // GEMM1: per wave 32 rows x 64 cols, K=256
        f32x4 acc1[2][4];
        #pragma unroll
        for (int mt = 0; mt < 2; ++mt)
            #pragma unroll
            for (int nt = 0; nt < 4; ++nt)
                acc1[mt][nt] = fzero;

        #pragma unroll
        for (int kk = 0; kk < 8; ++kk) {
            int k0 = kk * 32 + lg * 8;
            half8 bfr[4];
            #pragma unroll
            for (int nt = 0; nt < 4; ++nt) {
                int hr = nt * 16 + l15;
                bfr[nt] = *(const half8*)(W1sB + hr * 512 + ((k0 * 2) ^ ((hr & 7) << 4)));
            }
            #pragma unroll
            for (int mt = 0; mt < 2; ++mt)
                #pragma unroll
                for (int nt = 0; nt < 4; ++nt)
                    acc1[mt][nt] = __builtin_amdgcn_mfma_f32_16x16x32_f16(
                        afrag[mt][kk], bfr[nt], acc1[mt][nt], 0, 0, 0);
        }

        // bias + relu -> Hs (f16)
        #pragma unroll
        for (int nt = 0; nt < 4; ++nt) {
            int col = nt * 16 + l15;
            float bias = b1[t * HID + hc * HC + col];
            #pragma unroll
            for (int mt = 0; mt < 2; ++mt) {
                #pragma unroll
                for (int j = 0; j < 4; ++j) {
                    float v = fmaxf(acc1[mt][nt][j] + bias, 0.f);
                    int r = wave * 32 + mt * 16 + lg * 4 + j;
                    *(_Float16*)(HsB + r * 128 + ((col * 2) ^ ((r & 7) << 4))) = (_Float16)v;
                }
            }
        }
        __syncthreads();

        // GEMM2: acc2 += Hs(32 rows/wave) @ W2s, K=64
        #pragma unroll
        for (int kk = 0; kk < 2; ++kk) {
            int k0 = kk * 32 + lg * 8;
            half8 a2[2], b2f[2];
            #pragma unroll
            for (int mt = 0; mt < 2; ++mt) {
                int r = wave * 32 + mt * 16 + l15;
                a2[mt] = *(const half8*)(HsB + r * 128 + ((k0 * 2) ^ ((r & 7) << 4)));
            }
            #pragma unroll
            for (int nt = 0; nt < 2; ++nt) {
                int orow = nt * 16 + l15;
                b2f[nt] = *(const half8*)(W2sB + orow * 128 + ((k0 * 2) ^ ((orow & 7) << 4)));
            }
            #pragma unroll
            for (int mt = 0; mt < 2; ++mt)
                #pragma unroll
                for (int nt = 0; nt < 2; ++nt)
                    acc2[mt][nt] = __builtin_amdgcn_mfma_f32_16x16x32_f16(
                        a2[mt], b2f[nt], acc2[mt][nt], 0, 0, 0);
        }
    }

    // scatter-store
    const int m = min(BM, cnt - row_base);
    #pragma unroll
    for (int mt = 0; mt < 2; ++mt) {
        #pragma unroll
        for (int j = 0; j < 4; ++j) {
            int rloc = wave * 32 + mt * 16 + lg * 4 + j;
            if (rloc < m) {
                int gr = idx_t[row_base + rloc];
                #pragma unroll
                for (int nt = 0; nt < 2; ++nt) {
                    int col = nt * 16 + l15;
                    out[(size_t)gr * OUTD + col] = acc2[mt][nt][j] + b2[t * OUTD + col];
                }
            }
        }
    }
}

// ---------------- launch ----------------

extern "C" void kernel_launch(void* const* d_in, const int* in_sizes, int n_in,
                              void* d_out, int out_size, void* d_ws, size_t ws_size,
                              hipStream_t stream) {
    const float* x   = (const float*)d_in[0];
    const int* types = (const int*)d_in[1];
    const float* W1  = (const float*)d_in[2];
    const float* b1  = (const float*)d_in[3];
    const float* W2  = (const float*)d_in[4];
    const float* b2  = (const float*)d_in[5];
    float* out = (float*)d_out;

    char* ws = (char*)d_ws;
    int* meta = (int*)ws;                       // [0..3] counts, [4..7] offsets, [8..11] cursors
    int* idx = (int*)(ws + 64);                 // N_TOK int32
    _Float16* W1T = (_Float16*)(ws + 64 + 4 * (size_t)N_TOK);
    _Float16* W2T = W1T + (size_t)NTYPE * HID * DM;

    hipMemsetAsync(meta, 0, 48, stream);
    hist_kernel<<<512, 256, 0, stream>>>(types, meta);
    scan_kernel<<<1, 64, 0, stream>>>(meta);
    scatter_kernel<<<512, 256, 0, stream>>>(types, meta + 8, idx);
    wprep_kernel<<<(NTYPE * HID * DM) / 256, 256, 0, stream>>>(W1, W2, W1T, W2T);

    dim3 grid((N_TOK + BM - 1) / BM, NTYPE);
    fused_mlp_kernel<<<grid, 256, 0, stream>>>(x, meta, idx, W1T, W2T, b1, b2, out);
}

// Round 2
// 281.419 us; speedup vs baseline: 2.3838x; 2.3838x over previous
//
#include <hip/hip_runtime.h>
#include <hip/hip_bf16.h>
#include <hip/hip_fp16.h>

#define N_TOK 524288
#define DM 256
#define HID 512
#define OUTD 32
#define NTYPE 4
#define BM 128
#define HC 64
#define NBLK 512   // partition blocks; N_TOK = NBLK * 1024

typedef _Float16 half8 __attribute__((ext_vector_type(8)));
typedef float f32x4 __attribute__((ext_vector_type(4)));

// ---------------- deterministic atomic-free partition ----------------

// Phase 1: per-block per-type counts. Block b owns tokens [b*1024, b*1024+1024).
__global__ void count_kernel(const int* __restrict__ types, int* __restrict__ bc) {
    __shared__ int c[NTYPE];
    int tid = threadIdx.x;
    if (tid < NTYPE) c[tid] = 0;
    __syncthreads();
    int b = blockIdx.x;
    int lane = tid & 63;
    #pragma unroll
    for (int j = 0; j < 4; ++j) {
        int t = types[b * 1024 + j * 256 + tid];
        #pragma unroll
        for (int tt = 0; tt < NTYPE; ++tt) {
            unsigned long long mask = __ballot(t == tt);
            if (lane == 0) atomicAdd(&c[tt], __popcll(mask));
        }
    }
    __syncthreads();
    if (tid < NTYPE) bc[tid * NBLK + b] = c[tid];
}

// Phase 2: one block, wave t scans type t's 512 block counts.
// bb[t][b] = global base for block b's type-t tokens. meta: counts[4], offsets[4].
__global__ void scan_blocks_kernel(const int* __restrict__ bc,
                                   int* __restrict__ bb,
                                   int* __restrict__ meta) {
    __shared__ int totals[NTYPE];
    __shared__ int typeoff[NTYPE];
    int wave = threadIdx.x >> 6, lane = threadIdx.x & 63;
    int excl[NBLK / 64];
    int running = 0;
    #pragma unroll
    for (int it = 0; it < NBLK / 64; ++it) {
        int v = bc[wave * NBLK + it * 64 + lane];
        int s = v;
        #pragma unroll
        for (int d = 1; d < 64; d <<= 1) {
            int u = __shfl_up(s, d);
            if (lane >= d) s += u;
        }
        excl[it] = running + s - v;
        running += __shfl(s, 63);
    }
    if (lane == 0) totals[wave] = running;
    __syncthreads();
    if (threadIdx.x == 0) {
        int off = 0;
        for (int tt = 0; tt < NTYPE; ++tt) {
            typeoff[tt] = off;
            meta[tt] = totals[tt];
            meta[4 + tt] = off;
            off += totals[tt];
        }
    }
    __syncthreads();
    #pragma unroll
    for (int it = 0; it < NBLK / 64; ++it)
        bb[wave * NBLK + it * 64 + lane] = typeoff[wave] + excl[it];
}

// Phase 3: stable intra-block rank via ballot + cross-wave LDS prefix; no atomics.
__global__ void scatter2_kernel(const int* __restrict__ types,
                                const int* __restrict__ bb,
                                int* __restrict__ idx) {
    __shared__ int base[NTYPE];
    __shared__ int wcnt[4][NTYPE];
    int b = blockIdx.x;
    int tid = threadIdx.x, wave = tid >> 6, lane = tid & 63;
    if (tid < NTYPE) base[tid] = bb[tid * NBLK + b];
    #pragma unroll
    for (int j = 0; j < 4; ++j) {
        __syncthreads();  // base ready / previous update done
        int i = b * 1024 + j * 256 + tid;
        int t = types[i];
        int rank = 0;
        #pragma unroll
        for (int tt = 0; tt < NTYPE; ++tt) {
            unsigned long long mask = __ballot(t == tt);
            if (t == tt) rank = __popcll(mask & ((1ull << lane) - 1ull));
            if (lane == 0) wcnt[wave][tt] = __popcll(mask);
        }
        __syncthreads();  // wcnt ready
        int pre = 0;
        for (int w = 0; w < wave; ++w) pre += wcnt[w][t];
        idx[base[t] + pre + rank] = i;
        __syncthreads();  // all reads of base done
        if (tid < NTYPE) {
            int tot = 0;
            #pragma unroll
            for (int w = 0; w < 4; ++w) tot += wcnt[w][tid];
            base[tid] += tot;
        }
    }
}

// ---------------- weight prep (f32 -> f16, transposed) ----------------

__global__ void wprep_kernel(const float* __restrict__ W1, const float* __restrict__ W2,
                             _Float16* __restrict__ W1T, _Float16* __restrict__ W2T) {
    int i = blockIdx.x * blockDim.x + threadIdx.x;
    if (i < NTYPE * HID * DM) {
        int t = i / (HID * DM);
        int r = i - t * HID * DM;
        int h = r / DM;
        int d = r - h * DM;
        W1T[i] = (_Float16)W1[(t * DM + d) * HID + h];
    }
    if (i < NTYPE * OUTD * HID) {
        int t = i / (OUTD * HID);
        int r = i - t * OUTD * HID;
        int o = r / HID;
        int h = r - o * HID;
        W2T[i] = (_Float16)W2[(t * HID + h) * OUTD + o];
    }
}

// ---------------- fused grouped MLP ----------------
// Block: 256 threads (4 waves). Each block = 128 gathered rows of one type.
// X fragments live in registers. Per hidden-chunk (64): stage W1T/W2T chunk in
// swizzled LDS, GEMM1 -> relu -> Hs (LDS) -> GEMM2 accumulates persistent acc2.

__launch_bounds__(256)
__global__ void fused_mlp_kernel(const float* __restrict__ x,
                                 const int* __restrict__ meta,
                                 const int* __restrict__ idx,
                                 const _Float16* __restrict__ W1T,
                                 const _Float16* __restrict__ W2T,
                                 const float* __restrict__ b1,
                                 const float* __restrict__ b2,
                                 float* __restrict__ out) {
    const int t = blockIdx.y;
    const int cnt = meta[t];
    const int row_base = blockIdx.x * BM;
    if (row_base >= cnt) return;
    const int off = meta[4 + t];
    const int* idx_t = idx + off;

    __shared__ __align__(16) char W1sB[HC * 512];    // [64 h][256 d] f16, swizzled rows
    __shared__ __align__(16) char HsB[BM * 128];     // [128 m][64 h] f16, swizzled rows
    __shared__ __align__(16) char W2sB[OUTD * 128];  // [32 o][64 h] f16, swizzled rows

    const int tid = threadIdx.x;
    const int wave = tid >> 6;
    const int lane = tid & 63;
    const int l15 = lane & 15;
    const int lg = lane >> 4;  // 0..3

    // ---- load X fragments (gathered, fp32 -> f16) into registers ----
    half8 afrag[2][8];
    #pragma unroll
    for (int mt = 0; mt < 2; ++mt) {
        int rl = wave * 32 + mt * 16 + l15;
        int rglob = idx_t[min(row_base + rl, cnt - 1)];
        const float* xr = x + (size_t)rglob * DM;
        #pragma unroll
        for (int kk = 0; kk < 8; ++kk) {
            int k0 = kk * 32 + lg * 8;
            float4 v0 = *(const float4*)(xr + k0);
            float4 v1 = *(const float4*)(xr + k0 + 4);
            half8 h;
            h[0] = (_Float16)v0.x; h[1] = (_Float16)v0.y;
            h[2] = (_Float16)v0.z; h[3] = (_Float16)v0.w;
            h[4] = (_Float16)v1.x; h[5] = (_Float16)v1.y;
            h[6] = (_Float16)v1.z; h[7] = (_Float16)v1.w;
            afrag[mt][kk] = h;
        }
    }

    const f32x4 fzero = {0.f, 0.f, 0.f, 0.f};
    f32x4 acc2[2][2];
    #pragma unroll
    for (int mt = 0; mt < 2; ++mt)
        #pragma unroll
        for (int nt = 0; nt < 2; ++nt)
            acc2[mt][nt] = fzero;

    const _Float16* w1t_t = W1T + (size_t)t * HID * DM;   // [h][d]
    const _Float16* w2t_t = W2T + (size_t)t * OUTD * HID; // [o][h]

    for (int hc = 0; hc < HID / HC; ++hc) {
        __syncthreads();  // previous chunk's LDS readers done

        // stage W1 chunk: 64 rows x 256 f16 (2048 groups of 8)
        {
            const _Float16* src = w1t_t + hc * HC * DM;
            #pragma unroll
            for (int it = 0; it < 8; ++it) {
                int g = it * 256 + tid;
                int hr = g >> 5;
                int k0 = (g & 31) * 8;
                half8 v = *(const half8*)(src + hr * DM + k0);
                *(half8*)(W1sB + hr * 512 + ((k0 * 2) ^ ((hr & 7) << 4))) = v;
            }
        }
        // stage W2 chunk: 32 rows x 64 f16 (256 groups of 8)
        {
            int orow = tid >> 3;
            int k0 = (tid & 7) * 8;
            half8 v = *(const half8*)(w2t_t + orow * HID + hc * HC + k0);
            *(half8*)(W2sB + orow * 128 + ((k0 * 2) ^ ((orow & 7) << 4))) = v;
        }
        __syncthreads();

        // GEMM1: per wave 32 rows x 64 cols, K=256
        f32x4 acc1[2][4];
        #pragma unroll
        for (int mt = 0; mt < 2; ++mt)
            #pragma unroll
            for (int nt = 0; nt < 4; ++nt)
                acc1[mt][nt] = fzero;

        #pragma unroll
        for (int kk = 0; kk < 8; ++kk) {
            int k0 = kk * 32 + lg * 8;
            half8 bfr[4];
            #pragma unroll
            for (int nt = 0; nt < 4; ++nt) {
                int hr = nt * 16 + l15;
                bfr[nt] = *(const half8*)(W1sB + hr * 512 + ((k0 * 2) ^ ((hr & 7) << 4)));
            }
            #pragma unroll
            for (int mt = 0; mt < 2; ++mt)
                #pragma unroll
                for (int nt = 0; nt < 4; ++nt)
                    acc1[mt][nt] = __builtin_amdgcn_mfma_f32_16x16x32_f16(
                        afrag[mt][kk], bfr[nt], acc1[mt][nt], 0, 0, 0);
        }

        // bias + relu -> Hs (f16)
        #pragma unroll
        for (int nt = 0; nt < 4; ++nt) {
            int col = nt * 16 + l15;
            float bias = b1[t * HID + hc * HC + col];
            #pragma unroll
            for (int mt = 0; mt < 2; ++mt) {
                #pragma unroll
                for (int j = 0; j < 4; ++j) {
                    float v = fmaxf(acc1[mt][nt][j] + bias, 0.f);
                    int r = wave * 32 + mt * 16 + lg * 4 + j;
                    *(_Float16*)(HsB + r * 128 + ((col * 2) ^ ((r & 7) << 4))) = (_Float16)v;
                }
            }
        }
        __syncthreads();

        // GEMM2: acc2 += Hs(32 rows/wave) @ W2s, K=64
        #pragma unroll
        for (int kk = 0; kk < 2; ++kk) {
            int k0 = kk * 32 + lg * 8;
            half8 a2[2], b2f[2];
            #pragma unroll
            for (int mt = 0; mt < 2; ++mt) {
                int r = wave * 32 + mt * 16 + l15;
                a2[mt] = *(const half8*)(HsB + r * 128 + ((k0 * 2) ^ ((r & 7) << 4)));
            }
            #pragma unroll
            for (int nt = 0; nt < 2; ++nt) {
                int orow = nt * 16 + l15;
                b2f[nt] = *(const half8*)(W2sB + orow * 128 + ((k0 * 2) ^ ((orow & 7) << 4)));
            }
            #pragma unroll
            for (int mt = 0; mt < 2; ++mt)
                #pragma unroll
                for (int nt = 0; nt < 2; ++nt)
                    acc2[mt][nt] = __builtin_amdgcn_mfma_f32_16x16x32_f16(
                        a2[mt], b2f[nt], acc2[mt][nt], 0, 0, 0);
        }
    }

    // scatter-store
    const int m = min(BM, cnt - row_base);
    #pragma unroll
    for (int mt = 0; mt < 2; ++mt) {
        #pragma unroll
        for (int j = 0; j < 4; ++j) {
            int rloc = wave * 32 + mt * 16 + lg * 4 + j;
            if (rloc < m) {
                int gr = idx_t[row_base + rloc];
                #pragma unroll
                for (int nt = 0; nt < 2; ++nt) {
                    int col = nt * 16 + l15;
                    out[(size_t)gr * OUTD + col] = acc2[mt][nt][j] + b2[t * OUTD + col];
                }
            }
        }
    }
}

// ---------------- launch ----------------

extern "C" void kernel_launch(void* const* d_in, const int* in_sizes, int n_in,
                              void* d_out, int out_size, void* d_ws, size_t ws_size,
                              hipStream_t stream) {
    const float* x   = (const float*)d_in[0];
    const int* types = (const int*)d_in[1];
    const float* W1  = (const float*)d_in[2];
    const float* b1  = (const float*)d_in[3];
    const float* W2  = (const float*)d_in[4];
    const float* b2  = (const float*)d_in[5];
    float* out = (float*)d_out;

    char* ws = (char*)d_ws;
    int* meta = (int*)ws;                       // counts[4], offsets[4]
    int* idx = (int*)(ws + 64);                 // N_TOK int32
    _Float16* W1T = (_Float16*)(ws + 64 + 4 * (size_t)N_TOK);
    _Float16* W2T = W1T + (size_t)NTYPE * HID * DM;
    // bc/bb alias the W1T region: used only BEFORE wprep_kernel writes W1T
    // (same stream => ordered), saves workspace.
    int* bc = (int*)W1T;                        // [4][512]
    int* bb = bc + NTYPE * NBLK;                // [4][512]

    count_kernel<<<NBLK, 256, 0, stream>>>(types, bc);
    scan_blocks_kernel<<<1, 256, 0, stream>>>(bc, bb, meta);
    scatter2_kernel<<<NBLK, 256, 0, stream>>>(types, bb, idx);
    wprep_kernel<<<(NTYPE * HID * DM) / 256, 256, 0, stream>>>(W1, W2, W1T, W2T);

    dim3 grid((N_TOK + BM - 1) / BM, NTYPE);
    fused_mlp_kernel<<<grid, 256, 0, stream>>>(x, meta, idx, W1T, W2T, b1, b2, out);
}